// Round 1
// baseline (1373.650 us; speedup 1.0000x reference)
//
#include <hip/hip_runtime.h>

// Problem constants: B=2, C=256, planes=64, T=8, D=H=W=16
// spatial per batch S = T*D*H*W = 32768
#define S_TOT 32768

// ---------------------------------------------------------------------------
// K1: conv1x1 256->64.  y1[b][o][s] = sum_c w1[o][c] * x[b][c][s]
// grid 512 = b(2) x schunk(256, 128 s each); block 256 = og(8)x sg(32)
// thread: 8 o x 4 s register tile.
__global__ __launch_bounds__(256) void k_conv1(const float* __restrict__ x,
                                               const float* __restrict__ w1,
                                               float* __restrict__ y1) {
    __shared__ float wl[64 * 256];   // [o][c], 64 KiB
    int tid = threadIdx.x;
    for (int idx = tid; idx < 64 * 256; idx += 256) wl[idx] = w1[idx];
    __syncthreads();

    int blk = blockIdx.x;
    int b  = blk >> 8;
    int s0 = (blk & 255) * 128;
    int og = tid >> 5;          // 8 groups of 8 o
    int sg = tid & 31;          // 32 groups of 4 s
    int s  = s0 + sg * 4;

    float acc[8][4];
#pragma unroll
    for (int i = 0; i < 8; ++i)
#pragma unroll
        for (int j = 0; j < 4; ++j) acc[i][j] = 0.f;

    const float* xb = x + (size_t)b * 256 * S_TOT + s;
    for (int c = 0; c < 256; ++c) {
        float4 xv = *(const float4*)(xb + (size_t)c * S_TOT);
        const float* wp = &wl[og * 8 * 256 + c];
#pragma unroll
        for (int i = 0; i < 8; ++i) {
            float wv = wp[i * 256];   // wave-broadcast read
            acc[i][0] += wv * xv.x; acc[i][1] += wv * xv.y;
            acc[i][2] += wv * xv.z; acc[i][3] += wv * xv.w;
        }
    }
    float* yb = y1 + (size_t)b * 64 * S_TOT + s;
#pragma unroll
    for (int i = 0; i < 8; ++i) {
        int o = og * 8 + i;
        *(float4*)(yb + (size_t)o * S_TOT) =
            make_float4(acc[i][0], acc[i][1], acc[i][2], acc[i][3]);
    }
}

// ---------------------------------------------------------------------------
// BN stats: one block per channel; computes scale/shift for y = y*scale+shift
__global__ __launch_bounds__(256) void k_bnstats(const float* __restrict__ y, int nch,
                                                 const float* __restrict__ g,
                                                 const float* __restrict__ bb,
                                                 float* __restrict__ scale,
                                                 float* __restrict__ shift) {
    __shared__ float red[8];
    int ch = blockIdx.x, tid = threadIdx.x;
    float s = 0.f, q = 0.f;
    for (int b = 0; b < 2; ++b) {
        const float* p = y + ((size_t)b * nch + ch) * S_TOT;
        for (int i = tid * 4; i < S_TOT; i += 256 * 4) {
            float4 v = *(const float4*)(p + i);
            s += v.x + v.y + v.z + v.w;
            q += v.x * v.x + v.y * v.y + v.z * v.z + v.w * v.w;
        }
    }
#pragma unroll
    for (int off = 32; off; off >>= 1) {
        s += __shfl_down(s, off);
        q += __shfl_down(q, off);
    }
    int wid = tid >> 6;
    if ((tid & 63) == 0) { red[wid] = s; red[4 + wid] = q; }
    __syncthreads();
    if (tid == 0) {
        s = red[0] + red[1] + red[2] + red[3];
        q = red[4] + red[5] + red[6] + red[7];
        float n = 2.f * S_TOT;
        float m = s / n;
        float var = q / n - m * m;
        float rs = rsqrtf(var + 1e-5f);
        float sc = g[ch] * rs;
        scale[ch] = sc;
        shift[ch] = bb[ch] - m * sc;
    }
}

// ---------------------------------------------------------------------------
// K3: 4D conv 3x3x3x3, 64->64, input = relu(bn1(y1)) applied on the fly.
// grid 256 = (b,t,d); block 256 = og(8) x pg(32); thread: 8 o x 8 pos.
__global__ __launch_bounds__(256) void k_conv2(const float* __restrict__ y1,
                                               const float* __restrict__ w2,
                                               const float* __restrict__ sc1,
                                               const float* __restrict__ sh1,
                                               float* __restrict__ y2) {
    __shared__ float xs[18 * 18];     // padded (h,w) plane of one (c,tt,dd)
    __shared__ float ws[64 * 81];     // [o][r] weights for current c

    int tid = threadIdx.x;
    int blk = blockIdx.x;
    int b = blk >> 7, t = (blk >> 4) & 7, d = blk & 15;

    int og = tid & 7;                  // 8 groups of 8 o
    int pg = tid >> 3;                 // 32 groups of 8 positions
    int o_base = og * 8;
    int p  = pg * 8;
    int h  = p >> 4;
    int wb = p & 15;                   // 0 or 8

    float acc[8][8];
#pragma unroll
    for (int i = 0; i < 8; ++i)
#pragma unroll
        for (int j = 0; j < 8; ++j) acc[i][j] = 0.f;

    for (int c = 0; c < 64; ++c) {
        __syncthreads();   // previous iteration's reads of ws/xs done
        // stage weights for this c: ws[o*81 + r] = w2[o][c][r]
        for (int idx = tid; idx < 64 * 81; idx += 256) {
            int o = idx / 81;
            int r = idx - o * 81;
            ws[idx] = w2[((size_t)o * 64 + c) * 81 + r];
        }
        float a = sc1[c], bsh = sh1[c];

        for (int ktd = 0; ktd < 9; ++ktd) {
            int kt = ktd / 3, kd = ktd - kt * 3;
            int tt = t + kt - 1;
            int dd = d + kd - 1;
            __syncthreads();   // xs reads from previous tap done (also ws ready)
            bool inplane = (tt >= 0 && tt < 8 && dd >= 0 && dd < 16);
            const float* xp = y1 + (((size_t)(b * 64 + c) * 8 + tt) * 16 + dd) * 256;
            for (int idx = tid; idx < 324; idx += 256) {
                int i  = idx / 18;
                int j  = idx - i * 18;
                int hh = i - 1, ww = j - 1;
                float v = 0.f;
                if (inplane && hh >= 0 && hh < 16 && ww >= 0 && ww < 16) {
                    v = a * xp[hh * 16 + ww] + bsh;
                    v = v > 0.f ? v : 0.f;
                }
                xs[idx] = v;
            }
            __syncthreads();

#pragma unroll
            for (int kh = 0; kh < 3; ++kh) {
                float xrow[10];
                const float* xr = &xs[(h + kh) * 18 + wb];
#pragma unroll
                for (int j = 0; j < 10; ++j) xrow[j] = xr[j];
#pragma unroll
                for (int kw = 0; kw < 3; ++kw) {
                    int r = ktd * 9 + kh * 3 + kw;
                    float wv[8];
#pragma unroll
                    for (int i = 0; i < 8; ++i)
                        wv[i] = ws[(o_base + i) * 81 + r];  // wave-broadcast
#pragma unroll
                    for (int i = 0; i < 8; ++i)
#pragma unroll
                        for (int j = 0; j < 8; ++j)
                            acc[i][j] += wv[i] * xrow[kw + j];
                }
            }
        }
    }

#pragma unroll
    for (int i = 0; i < 8; ++i) {
        int o = o_base + i;
        float* row = y2 + ((((size_t)(b * 64 + o) * 8 + t) * 16 + d) * 256) + h * 16 + wb;
        *(float4*)(row)     = make_float4(acc[i][0], acc[i][1], acc[i][2], acc[i][3]);
        *(float4*)(row + 4) = make_float4(acc[i][4], acc[i][5], acc[i][6], acc[i][7]);
    }
}

// ---------------------------------------------------------------------------
// K5: conv1x1 64->256, input = relu(bn2(y2)) on the fly; writes y3 (into d_out).
// grid 2048 = oc(4) x b(2) x schunk(256); block 256 = og(8) x sg(32)
__global__ __launch_bounds__(256) void k_conv3(const float* __restrict__ y2,
                                               const float* __restrict__ w3,
                                               const float* __restrict__ sc2,
                                               const float* __restrict__ sh2,
                                               float* __restrict__ y3) {
    __shared__ float wl[64 * 64];   // [o-local][c], 16 KiB
    int tid = threadIdx.x;
    int blk = blockIdx.x;
    int oc = blk >> 9;
    int b  = (blk >> 8) & 1;
    int s0 = (blk & 255) * 128;

    for (int idx = tid; idx < 4096; idx += 256) wl[idx] = w3[(size_t)oc * 4096 + idx];
    __syncthreads();

    int og = tid >> 5, sg = tid & 31;
    int s = s0 + sg * 4;

    float acc[8][4];
#pragma unroll
    for (int i = 0; i < 8; ++i)
#pragma unroll
        for (int j = 0; j < 4; ++j) acc[i][j] = 0.f;

    const float* yb = y2 + (size_t)b * 64 * S_TOT + s;
    for (int c = 0; c < 64; ++c) {
        float a = sc2[c], bsh = sh2[c];
        float4 v = *(const float4*)(yb + (size_t)c * S_TOT);
        float4 xv;
        xv.x = fmaxf(a * v.x + bsh, 0.f);
        xv.y = fmaxf(a * v.y + bsh, 0.f);
        xv.z = fmaxf(a * v.z + bsh, 0.f);
        xv.w = fmaxf(a * v.w + bsh, 0.f);
        const float* wp = &wl[og * 8 * 64 + c];
#pragma unroll
        for (int i = 0; i < 8; ++i) {
            float wv = wp[i * 64];   // wave-broadcast
            acc[i][0] += wv * xv.x; acc[i][1] += wv * xv.y;
            acc[i][2] += wv * xv.z; acc[i][3] += wv * xv.w;
        }
    }
#pragma unroll
    for (int i = 0; i < 8; ++i) {
        int o = oc * 64 + og * 8 + i;
        *(float4*)(y3 + ((size_t)b * 256 + o) * S_TOT + s) =
            make_float4(acc[i][0], acc[i][1], acc[i][2], acc[i][3]);
    }
}

// ---------------------------------------------------------------------------
// K7: out = relu(bn3(y3) + x), in place on d_out (which holds y3).
__global__ __launch_bounds__(256) void k_final(const float* __restrict__ x,
                                               const float* __restrict__ sc3,
                                               const float* __restrict__ sh3,
                                               float* __restrict__ out) {
    size_t i = ((size_t)blockIdx.x * 256 + threadIdx.x) * 4;
    int o = (int)((i >> 15) & 255);
    float a = sc3[o], bsh = sh3[o];
    float4 y = *(float4*)(out + i);
    float4 xv = *(const float4*)(x + i);
    float4 r;
    r.x = fmaxf(a * y.x + bsh + xv.x, 0.f);
    r.y = fmaxf(a * y.y + bsh + xv.y, 0.f);
    r.z = fmaxf(a * y.z + bsh + xv.z, 0.f);
    r.w = fmaxf(a * y.w + bsh + xv.w, 0.f);
    *(float4*)(out + i) = r;
}

// ---------------------------------------------------------------------------
extern "C" void kernel_launch(void* const* d_in, const int* in_sizes, int n_in,
                              void* d_out, int out_size, void* d_ws, size_t ws_size,
                              hipStream_t stream) {
    const float* x  = (const float*)d_in[0];
    const float* w1 = (const float*)d_in[1];
    const float* g1 = (const float*)d_in[2];
    const float* b1 = (const float*)d_in[3];
    const float* w2 = (const float*)d_in[4];
    const float* g2 = (const float*)d_in[5];
    const float* b2 = (const float*)d_in[6];
    const float* w3 = (const float*)d_in[7];
    const float* g3 = (const float*)d_in[8];
    const float* b3 = (const float*)d_in[9];

    float* wsf = (float*)d_ws;
    float* y1 = wsf;                         // 2*64*32768 = 4194304 floats
    float* y2 = wsf + 4194304;               // 4194304 floats
    float* st = wsf + 8388608;               // stats: 768 floats
    float* sc1 = st;        float* sh1 = st + 64;
    float* sc2 = st + 128;  float* sh2 = st + 192;
    float* sc3 = st + 256;  float* sh3 = st + 512;
    float* y3 = (float*)d_out;               // reuse output buffer as y3 scratch

    k_conv1  <<<512,   256, 0, stream>>>(x, w1, y1);
    k_bnstats<<<64,    256, 0, stream>>>(y1, 64, g1, b1, sc1, sh1);
    k_conv2  <<<256,   256, 0, stream>>>(y1, w2, sc1, sh1, y2);
    k_bnstats<<<64,    256, 0, stream>>>(y2, 64, g2, b2, sc2, sh2);
    k_conv3  <<<2048,  256, 0, stream>>>(y2, w3, sc2, sh2, y3);
    k_bnstats<<<256,   256, 0, stream>>>(y3, 256, g3, b3, sc3, sh3);
    k_final  <<<16384, 256, 0, stream>>>(x, sc3, sh3, y3);
}

// Round 2
// 335.765 us; speedup vs baseline: 4.0911x; 4.0911x over previous
//
#include <hip/hip_runtime.h>

// Problem constants: B=2, C=256, planes=64, T=8, D=H=W=16
// spatial per batch S = T*D*H*W = 32768
#define S_TOT 32768

typedef unsigned short ushortT;
typedef __attribute__((ext_vector_type(8))) short short8;
typedef __attribute__((ext_vector_type(4))) float floatx4;

__device__ __forceinline__ ushortT f2bf(float f) {
    unsigned u = __float_as_uint(f);
    u = (u + 0x7fffu + ((u >> 16) & 1u)) >> 16;
    return (ushortT)u;
}

// ---------------------------------------------------------------------------
// K1: conv1x1 256->64.  y1[b][o][s] = sum_c w1[o][c] * x[b][c][s]
__global__ __launch_bounds__(256) void k_conv1(const float* __restrict__ x,
                                               const float* __restrict__ w1,
                                               float* __restrict__ y1) {
    __shared__ float wl[64 * 256];
    int tid = threadIdx.x;
    for (int idx = tid; idx < 64 * 256; idx += 256) wl[idx] = w1[idx];
    __syncthreads();

    int blk = blockIdx.x;
    int b  = blk >> 8;
    int s0 = (blk & 255) * 128;
    int og = tid >> 5;
    int sg = tid & 31;
    int s  = s0 + sg * 4;

    float acc[8][4];
#pragma unroll
    for (int i = 0; i < 8; ++i)
#pragma unroll
        for (int j = 0; j < 4; ++j) acc[i][j] = 0.f;

    const float* xb = x + (size_t)b * 256 * S_TOT + s;
    for (int c = 0; c < 256; ++c) {
        float4 xv = *(const float4*)(xb + (size_t)c * S_TOT);
        const float* wp = &wl[og * 8 * 256 + c];
#pragma unroll
        for (int i = 0; i < 8; ++i) {
            float wv = wp[i * 256];
            acc[i][0] += wv * xv.x; acc[i][1] += wv * xv.y;
            acc[i][2] += wv * xv.z; acc[i][3] += wv * xv.w;
        }
    }
    float* yb = y1 + (size_t)b * 64 * S_TOT + s;
#pragma unroll
    for (int i = 0; i < 8; ++i) {
        int o = og * 8 + i;
        *(float4*)(yb + (size_t)o * S_TOT) =
            make_float4(acc[i][0], acc[i][1], acc[i][2], acc[i][3]);
    }
}

// ---------------------------------------------------------------------------
// BN stats: one block per channel; computes scale/shift for y = y*scale+shift
__global__ __launch_bounds__(256) void k_bnstats(const float* __restrict__ y, int nch,
                                                 const float* __restrict__ g,
                                                 const float* __restrict__ bb,
                                                 float* __restrict__ scale,
                                                 float* __restrict__ shift) {
    __shared__ float red[8];
    int ch = blockIdx.x, tid = threadIdx.x;
    float s = 0.f, q = 0.f;
    for (int b = 0; b < 2; ++b) {
        const float* p = y + ((size_t)b * nch + ch) * S_TOT;
        for (int i = tid * 4; i < S_TOT; i += 256 * 4) {
            float4 v = *(const float4*)(p + i);
            s += v.x + v.y + v.z + v.w;
            q += v.x * v.x + v.y * v.y + v.z * v.z + v.w * v.w;
        }
    }
#pragma unroll
    for (int off = 32; off; off >>= 1) {
        s += __shfl_down(s, off);
        q += __shfl_down(q, off);
    }
    int wid = tid >> 6;
    if ((tid & 63) == 0) { red[wid] = s; red[4 + wid] = q; }
    __syncthreads();
    if (tid == 0) {
        s = red[0] + red[1] + red[2] + red[3];
        q = red[4] + red[5] + red[6] + red[7];
        float n = 2.f * S_TOT;
        float m = s / n;
        float var = q / n - m * m;
        float rs = rsqrtf(var + 1e-5f);
        float sc = g[ch] * rs;
        scale[ch] = sc;
        shift[ch] = bb[ch] - m * sc;
    }
}

// ---------------------------------------------------------------------------
// Prep X: y1n = bf16(relu(sc1*y1 + sh1)), same layout [b][c][t*d*h*w]
__global__ __launch_bounds__(256) void k_prep_x(const float* __restrict__ y1,
                                                const float* __restrict__ sc,
                                                const float* __restrict__ sh,
                                                ushortT* __restrict__ y1n) {
    size_t i = ((size_t)blockIdx.x * 256 + threadIdx.x) * 4;
    int c = (int)((i >> 15) & 63);
    float a = sc[c], b = sh[c];
    float4 v = *(const float4*)(y1 + i);
    ushort4 r;
    r.x = f2bf(fmaxf(a * v.x + b, 0.f));
    r.y = f2bf(fmaxf(a * v.y + b, 0.f));
    r.z = f2bf(fmaxf(a * v.z + b, 0.f));
    r.w = f2bf(fmaxf(a * v.w + b, 0.f));
    *(ushort4*)(y1n + i) = r;
}

// ---------------------------------------------------------------------------
// Prep W2: repack w2 fp32 [o][c][81] -> bf16 wb2[tap][cb(8)][o(64)][j(8)]
// so an A-fragment (lane m=o&15, q: c = ks*32+q*8+j) is one contiguous 16B load.
__global__ __launch_bounds__(256) void k_prep_w2(const float* __restrict__ w2,
                                                 ushortT* __restrict__ wb2) {
    int idx = blockIdx.x * 256 + threadIdx.x;   // < 331776
    int j   = idx & 7;
    int o   = (idx >> 3) & 63;
    int cb  = (idx >> 9) & 7;
    int tap = idx >> 12;
    int c   = cb * 8 + j;
    wb2[idx] = f2bf(w2[((size_t)o * 64 + c) * 81 + tap]);
}

// ---------------------------------------------------------------------------
// K3: conv 3x3x3x3, 64->64 as bf16 MFMA implicit GEMM.
// grid 512 = (b, t, d, h-half); block 256 = 4 waves, wave wv owns o-tile wv*16.
// Per (kt,kd): stage padded 10x18 (h,w) plane x 64ch transposed into LDS
// ([pos][c], stride 72 bf16); A-frags (9 taps x 2 ksteps) kept in registers.
__global__ __launch_bounds__(256, 2) void k_conv2_mfma(
        const ushortT* __restrict__ y1n,   // [b][c][t][d][h][w] bf16
        const ushortT* __restrict__ wb2,   // [tap][cb][o][j] bf16
        float* __restrict__ y2) {
    __shared__ __align__(16) ushortT xs[180 * 72];

    int tid = threadIdx.x;
    int blk = blockIdx.x;
    int b  = blk >> 8;
    int t  = (blk >> 5) & 7;
    int d  = (blk >> 1) & 15;
    int h0 = (blk & 1) * 8;

    int lane = tid & 63;
    int wv   = tid >> 6;       // o-tile: o in [wv*16, wv*16+16)
    int m    = lane & 15;
    int q    = lane >> 4;

    // staging role: channels (2*c2, 2*c2+1), padded rows prbase, prbase+8
    int c2      = tid & 31;
    int prbase  = tid >> 5;

    floatx4 acc[8];
#pragma unroll
    for (int i = 0; i < 8; ++i) acc[i] = (floatx4){0.f, 0.f, 0.f, 0.f};

    const size_t cstride = 32768;   // y1n channel stride (8*16*16*16)
    uint32_t* xsd = (uint32_t*)xs;  // dword view: dword idx = pos*36 + c2

    for (int ktd = 0; ktd < 9; ++ktd) {
        int kt = ktd / 3, kd = ktd - kt * 3;
        int tt = t + kt - 1;
        int dd = d + kd - 1;
        bool pv = (tt >= 0 && tt < 8 && dd >= 0 && dd < 16);

        // A-fragments for the 9 (kh,kw) taps of this (kt,kd): global loads (L2-hot)
        short8 afr[9][2];
#pragma unroll
        for (int khw = 0; khw < 9; ++khw) {
#pragma unroll
            for (int ks = 0; ks < 2; ++ks) {
                int tap = ktd * 9 + khw;
                const ushortT* wp =
                    wb2 + (((size_t)(tap * 8 + ks * 4 + q)) * 64 + wv * 16 + m) * 8;
                afr[khw][ks] = *(const short8*)wp;
            }
        }

        __syncthreads();   // previous iteration's LDS reads complete

        // stage transposed padded plane
        for (int pr = prbase; pr < 10; pr += 8) {
            int hin = h0 + pr - 1;
            uint32_t pack[18];
            if (pv && hin >= 0 && hin < 16) {
                const ushortT* p0 = y1n +
                    (((size_t)(b * 64 + 2 * c2) * 8 + tt) * 16 + dd) * 256 + hin * 16;
                const ushortT* p1 = p0 + cstride;
                uint4 r0 = *(const uint4*)p0;
                uint4 r1 = *(const uint4*)(p0 + 8);
                uint4 s0 = *(const uint4*)p1;
                uint4 s1 = *(const uint4*)(p1 + 8);
                uint32_t ra[8] = {r0.x, r0.y, r0.z, r0.w, r1.x, r1.y, r1.z, r1.w};
                uint32_t sa[8] = {s0.x, s0.y, s0.z, s0.w, s1.x, s1.y, s1.z, s1.w};
                pack[0] = 0; pack[17] = 0;
#pragma unroll
                for (int k = 0; k < 8; ++k) {
                    pack[1 + 2 * k] = (ra[k] & 0xffffu) | (sa[k] << 16);
                    pack[2 + 2 * k] = (ra[k] >> 16) | (sa[k] & 0xffff0000u);
                }
            } else {
#pragma unroll
                for (int k = 0; k < 18; ++k) pack[k] = 0;
            }
            int base = pr * 18 * 36 + c2;
#pragma unroll
            for (int k = 0; k < 18; ++k) xsd[base + k * 36] = pack[k];
        }
        __syncthreads();

        // compute: 9 taps x 8 pos-tiles x 2 ksteps
#pragma unroll
        for (int khw = 0; khw < 9; ++khw) {
            int kh = khw / 3, kw = khw - kh * 3;
#pragma unroll
            for (int nt = 0; nt < 8; ++nt) {
                int ppos = (nt + kh) * 18 + m + kw;
                const ushortT* bp = xs + ppos * 72 + q * 8;
                short8 b0 = *(const short8*)bp;
                short8 b1 = *(const short8*)(bp + 32);
                acc[nt] = __builtin_amdgcn_mfma_f32_16x16x32_bf16(
                    afr[khw][0], b0, acc[nt], 0, 0, 0);
                acc[nt] = __builtin_amdgcn_mfma_f32_16x16x32_bf16(
                    afr[khw][1], b1, acc[nt], 0, 0, 0);
            }
        }
    }

    // store: C row = o_local = q*4+reg, col = pos = nt*16+m
#pragma unroll
    for (int nt = 0; nt < 8; ++nt) {
#pragma unroll
        for (int r = 0; r < 4; ++r) {
            int o = wv * 16 + q * 4 + r;
            y2[(((size_t)(b * 64 + o) * 8 + t) * 16 + d) * 256 + (h0 + nt) * 16 + m] =
                acc[nt][r];
        }
    }
}

// ---------------------------------------------------------------------------
// K5: conv1x1 64->256, input = relu(bn2(y2)) on the fly; writes y3 (into d_out).
__global__ __launch_bounds__(256) void k_conv3(const float* __restrict__ y2,
                                               const float* __restrict__ w3,
                                               const float* __restrict__ sc2,
                                               const float* __restrict__ sh2,
                                               float* __restrict__ y3) {
    __shared__ float wl[64 * 64];
    int tid = threadIdx.x;
    int blk = blockIdx.x;
    int oc = blk >> 9;
    int b  = (blk >> 8) & 1;
    int s0 = (blk & 255) * 128;

    for (int idx = tid; idx < 4096; idx += 256) wl[idx] = w3[(size_t)oc * 4096 + idx];
    __syncthreads();

    int og = tid >> 5, sg = tid & 31;
    int s = s0 + sg * 4;

    float acc[8][4];
#pragma unroll
    for (int i = 0; i < 8; ++i)
#pragma unroll
        for (int j = 0; j < 4; ++j) acc[i][j] = 0.f;

    const float* yb = y2 + (size_t)b * 64 * S_TOT + s;
    for (int c = 0; c < 64; ++c) {
        float a = sc2[c], bsh = sh2[c];
        float4 v = *(const float4*)(yb + (size_t)c * S_TOT);
        float4 xv;
        xv.x = fmaxf(a * v.x + bsh, 0.f);
        xv.y = fmaxf(a * v.y + bsh, 0.f);
        xv.z = fmaxf(a * v.z + bsh, 0.f);
        xv.w = fmaxf(a * v.w + bsh, 0.f);
        const float* wp = &wl[og * 8 * 64 + c];
#pragma unroll
        for (int i = 0; i < 8; ++i) {
            float wv = wp[i * 64];
            acc[i][0] += wv * xv.x; acc[i][1] += wv * xv.y;
            acc[i][2] += wv * xv.z; acc[i][3] += wv * xv.w;
        }
    }
#pragma unroll
    for (int i = 0; i < 8; ++i) {
        int o = oc * 64 + og * 8 + i;
        *(float4*)(y3 + ((size_t)b * 256 + o) * S_TOT + s) =
            make_float4(acc[i][0], acc[i][1], acc[i][2], acc[i][3]);
    }
}

// ---------------------------------------------------------------------------
// K7: out = relu(bn3(y3) + x), in place on d_out (which holds y3).
__global__ __launch_bounds__(256) void k_final(const float* __restrict__ x,
                                               const float* __restrict__ sc3,
                                               const float* __restrict__ sh3,
                                               float* __restrict__ out) {
    size_t i = ((size_t)blockIdx.x * 256 + threadIdx.x) * 4;
    int o = (int)((i >> 15) & 255);
    float a = sc3[o], bsh = sh3[o];
    float4 y = *(float4*)(out + i);
    float4 xv = *(const float4*)(x + i);
    float4 r;
    r.x = fmaxf(a * y.x + bsh + xv.x, 0.f);
    r.y = fmaxf(a * y.y + bsh + xv.y, 0.f);
    r.z = fmaxf(a * y.z + bsh + xv.z, 0.f);
    r.w = fmaxf(a * y.w + bsh + xv.w, 0.f);
    *(float4*)(out + i) = r;
}

// ---------------------------------------------------------------------------
extern "C" void kernel_launch(void* const* d_in, const int* in_sizes, int n_in,
                              void* d_out, int out_size, void* d_ws, size_t ws_size,
                              hipStream_t stream) {
    const float* x  = (const float*)d_in[0];
    const float* w1 = (const float*)d_in[1];
    const float* g1 = (const float*)d_in[2];
    const float* b1 = (const float*)d_in[3];
    const float* w2 = (const float*)d_in[4];
    const float* g2 = (const float*)d_in[5];
    const float* b2 = (const float*)d_in[6];
    const float* w3 = (const float*)d_in[7];
    const float* g3 = (const float*)d_in[8];
    const float* b3 = (const float*)d_in[9];

    float* wsf = (float*)d_ws;
    float* y1 = wsf;                         // 4194304 floats
    float* y2 = wsf + 4194304;               // 4194304 floats
    float* st = wsf + 8388608;               // stats: 768 floats
    float* sc1 = st;        float* sh1 = st + 64;
    float* sc2 = st + 128;  float* sh2 = st + 192;
    float* sc3 = st + 256;  float* sh3 = st + 512;
    ushortT* wb2 = (ushortT*)(wsf + 8389376);  // 331776 bf16
    // y1n (bf16 of relu(bn1(y1))) lives in d_out until k_conv3 overwrites it.
    ushortT* y1n = (ushortT*)d_out;
    float* y3 = (float*)d_out;

    k_conv1   <<<512,   256, 0, stream>>>(x, w1, y1);
    k_bnstats <<<64,    256, 0, stream>>>(y1, 64, g1, b1, sc1, sh1);
    k_prep_x  <<<4096,  256, 0, stream>>>(y1, sc1, sh1, y1n);
    k_prep_w2 <<<1296,  256, 0, stream>>>(w2, wb2);
    k_conv2_mfma<<<512, 256, 0, stream>>>(y1n, wb2, y2);
    k_bnstats <<<64,    256, 0, stream>>>(y2, 64, g2, b2, sc2, sh2);
    k_conv3   <<<2048,  256, 0, stream>>>(y2, w3, sc2, sh2, y3);
    k_bnstats <<<256,   256, 0, stream>>>(y3, 256, g3, b3, sc3, sh3);
    k_final   <<<16384, 256, 0, stream>>>(x, sc3, sh3, y3);
}